// Round 11
// baseline (475.636 us; speedup 1.0000x reference)
//
#include <hip/hip_runtime.h>
#include <cstdint>
#include <cstddef>

typedef __attribute__((ext_vector_type(8))) short short8;
typedef __attribute__((ext_vector_type(4))) float f32x4;

// ---------- helpers ----------
__device__ __forceinline__ unsigned short f2bf(float x) {
  union { float f; unsigned u; } v; v.f = x;
  unsigned r = (v.u + 0x7FFFu + ((v.u >> 16) & 1u)) >> 16;
  return (unsigned short)r;
}

#define GLOAD16(g, l)                                                    \
  __builtin_amdgcn_global_load_lds(                                      \
      (const __attribute__((address_space(1))) unsigned int*)(g),        \
      (__attribute__((address_space(3))) unsigned int*)(l), 16, 0, 0)

// ---------- f32 -> bf16 conversion (memory-bound) ----------
__global__ __launch_bounds__(256) void cvt_f32_bf16(
    const float* __restrict__ in, unsigned short* __restrict__ out, long n) {
  long i = ((long)blockIdx.x * 256 + threadIdx.x) * 8;
  if (i >= n) return;
  const float4* p = (const float4*)(in + i);
  float4 a = p[0], b = p[1];
  short8 r;
  r[0] = (short)f2bf(a.x); r[1] = (short)f2bf(a.y);
  r[2] = (short)f2bf(a.z); r[3] = (short)f2bf(a.w);
  r[4] = (short)f2bf(b.x); r[5] = (short)f2bf(b.y);
  r[6] = (short)f2bf(b.z); r[7] = (short)f2bf(b.w);
  *(short8*)(out + i) = r;
}

// ---------- gemm_bt256: C[b][m,n] = f( sum_k A[b][m,k]*B[b][n,k] ) -------
// MODE 1: bf16 out (val*scale)
// MODE 2: bf16 out, exp(val*scale); atomicAdd per-row sums into rs
// MODE 3: f32 out, val / rs[row]
// 256x256 tile, 8 waves (2M x 4N), BK=64, double-buffered LDS (128 KiB).
// Skeleton = r5 exactly (best measured across r2-r10):
//   { sched_barrier(0); barrier A (buf[cur^1] reads done);
//     STAGE(j+1, cur^1); vmcnt(8) -- waits only tile j's loads, the 8 just
//     issued stay in flight across compute; barrier B (tile j landed);
//     plain C++ ds_reads + MFMAs, compiler-scheduled counted lgkm }
// Epilogues = r9 (rowsum via atomics in MODE 2; PV divide-only MODE 3).
// LDS swizzle: 16B slot ^= (row&7); inverse applied on global source.
// Requires M%256==0, N%256==0, K%64==0, gridDim.x%8==0.
template <int MODE>
__global__ __launch_bounds__(512, 2) void gemm_bt256(
    const unsigned short* __restrict__ A, int lda, size_t asb,
    const unsigned short* __restrict__ B, int ldb, size_t bsb,
    void* __restrict__ C, int ldc, size_t csb,
    float* __restrict__ rs, int rss,
    int nbn, int K, float scale) {
  __shared__ unsigned short As[2][256 * 64];
  __shared__ unsigned short Bs[2][256 * 64];

  A += (size_t)blockIdx.y * asb;
  B += (size_t)blockIdx.y * bsb;
  char* Cb = (char*)C + (size_t)blockIdx.y * csb * (MODE == 3 ? 4 : 2);
  rs += (size_t)blockIdx.y * rss;

  // XCD-aware block swizzle (gridDim.x multiple of 8)
  unsigned bid = blockIdx.x;
  unsigned cpx = gridDim.x >> 3;
  unsigned swz = (bid & 7u) * cpx + (bid >> 3);
  int bm = (int)(swz / (unsigned)nbn);
  int bn = (int)(swz % (unsigned)nbn);
  int m0 = bm * 256, n0 = bn * 256;

  int t512 = threadIdx.x;
  int lane = t512 & 63, wid = t512 >> 6;
  int wm = wid >> 2, wn = wid & 3;           // 2 x 4 wave grid
  int l15 = lane & 15, l4 = lane >> 4;

  // staging: thread t handles 16B chunks at rows srow+{0,64,128,192};
  // LDS slot = t&7 (linear dest), global chunk = slot ^ (srow&7).
  int srow = t512 >> 3;
  int g = (t512 & 7) ^ ((t512 >> 3) & 7);
  const unsigned short* pa = A + (size_t)(m0 + srow) * lda + g * 8;
  const unsigned short* pb = B + (size_t)(n0 + srow) * ldb + g * 8;

  f32x4 acc[8][4] = {};

  const int NT = K >> 6;

#define STAGE(jj, buf)                                                    \
  do {                                                                    \
    int _k0 = (jj) << 6;                                                  \
    _Pragma("unroll") for (int i = 0; i < 4; i++)                         \
        GLOAD16(pa + (size_t)(i * 64) * lda + _k0,                        \
                (char*)As[buf] + i * 8192 + t512 * 16);                   \
    _Pragma("unroll") for (int i = 0; i < 4; i++)                         \
        GLOAD16(pb + (size_t)(i * 64) * ldb + _k0,                        \
                (char*)Bs[buf] + i * 8192 + t512 * 16);                   \
  } while (0)

  // prologue: stage tile 0 into buffer 0
  STAGE(0, 0);

  for (int j = 0; j < NT; ++j) {
    int cur = j & 1;
    // pin all of iteration j-1's reads/MFMAs before the stage below
    __builtin_amdgcn_sched_barrier(0);
    // barrier A: all waves done with buf[cur^1] (tile j-1)
    __builtin_amdgcn_s_barrier();
    if (j + 1 < NT) {
      STAGE(j + 1, cur ^ 1);
      // wait ONLY for tile j's 8 loads; the 8 just issued stay in flight
      asm volatile("s_waitcnt vmcnt(8)" ::: "memory");
    } else {
      asm volatile("s_waitcnt vmcnt(0)" ::: "memory");
    }
    // barrier B: every wave's tile-j loads have landed
    __builtin_amdgcn_s_barrier();

    const char* Ab = (const char*)As[cur];
    const char* Bb = (const char*)Bs[cur];

    // plain reads; compiler interleaves with MFMAs via counted lgkmcnt
    short8 bfv[4][2], afv[8][2];
#pragma unroll
    for (int ni = 0; ni < 4; ni++)
#pragma unroll
      for (int ks = 0; ks < 2; ks++) {
        int r = wn * 64 + ni * 16 + l15;
        int c = ((ks << 2) | l4) ^ (r & 7);
        bfv[ni][ks] = *(const short8*)(Bb + r * 128 + c * 16);
      }
#pragma unroll
    for (int mi = 0; mi < 8; mi++)
#pragma unroll
      for (int ks = 0; ks < 2; ks++) {
        int r = wm * 128 + mi * 16 + l15;
        int c = ((ks << 2) | l4) ^ (r & 7);
        afv[mi][ks] = *(const short8*)(Ab + r * 128 + c * 16);
      }
#pragma unroll
    for (int ks = 0; ks < 2; ks++)
#pragma unroll
      for (int mi = 0; mi < 8; mi++)
#pragma unroll
        for (int ni = 0; ni < 4; ni++)
          acc[mi][ni] = __builtin_amdgcn_mfma_f32_16x16x32_bf16(
              afv[mi][ks], bfv[ni][ks], acc[mi][ni], 0, 0, 0);
  }
#undef STAGE

  // epilogue; row = m0 + wm*128 + mi*16 + l4*4 + jj, col = n0 + wn*64 + ni*16 + l15
  if constexpr (MODE == 2) {
    float sums[8][4];
#pragma unroll
    for (int mi = 0; mi < 8; mi++)
#pragma unroll
      for (int jj = 0; jj < 4; jj++) sums[mi][jj] = 0.f;
#pragma unroll
    for (int mi = 0; mi < 8; mi++)
#pragma unroll
      for (int ni = 0; ni < 4; ni++)
#pragma unroll
        for (int jj = 0; jj < 4; jj++) {
          int row = m0 + wm * 128 + mi * 16 + l4 * 4 + jj;
          int col = n0 + wn * 64 + ni * 16 + l15;
          float e = __expf(acc[mi][ni][jj] * scale);
          sums[mi][jj] += e;
          ((unsigned short*)Cb)[(size_t)row * ldc + col] = f2bf(e);
        }
    // reduce the 16 col-lanes (l15) of each row group, one atomic per group
#pragma unroll
    for (int mi = 0; mi < 8; mi++)
#pragma unroll
      for (int jj = 0; jj < 4; jj++) {
        float s = sums[mi][jj];
        s += __shfl_xor(s, 1);
        s += __shfl_xor(s, 2);
        s += __shfl_xor(s, 4);
        s += __shfl_xor(s, 8);
        if (l15 == 0) {
          int row = m0 + wm * 128 + mi * 16 + l4 * 4 + jj;
          atomicAdd(&rs[row], s);
        }
      }
  } else {
#pragma unroll
    for (int mi = 0; mi < 8; mi++) {
      float inv[4];
      if constexpr (MODE == 3) {
#pragma unroll
        for (int jj = 0; jj < 4; jj++) {
          int row = m0 + wm * 128 + mi * 16 + l4 * 4 + jj;
          inv[jj] = 1.0f / rs[row];
        }
      }
#pragma unroll
      for (int ni = 0; ni < 4; ni++)
#pragma unroll
        for (int jj = 0; jj < 4; jj++) {
          int row = m0 + wm * 128 + mi * 16 + l4 * 4 + jj;
          int col = n0 + wn * 64 + ni * 16 + l15;
          float val = acc[mi][ni][jj];
          if constexpr (MODE == 1)
            ((unsigned short*)Cb)[(size_t)row * ldc + col] = f2bf(val * scale);
          else
            ((float*)Cb)[(size_t)row * ldc + col] = val * inv[jj];
        }
    }
  }
}

// ---------- launcher ----------
extern "C" void kernel_launch(void* const* d_in, const int* in_sizes, int n_in,
                              void* d_out, int out_size, void* d_ws, size_t ws_size,
                              hipStream_t stream) {
  (void)in_sizes; (void)n_in; (void)out_size;
  const float* x  = (const float*)d_in[0];
  const float* Wq = (const float*)d_in[1];
  const float* Wk = (const float*)d_in[2];
  const float* Wv = (const float*)d_in[3];
  float* out = (float*)d_out;

  const int Bn = 4, S = 4096, D = 1024;
  const size_t MS = (size_t)Bn * S;  // 16384
  const float scale = 0.03125f;      // 1/sqrt(1024)

  // ---- workspace layout ----
  char* ws = (char*)d_ws;
  unsigned short* QKb = (unsigned short*)ws; ws += MS * 2048 * 2;        // 64 MiB
  unsigned short* VTb = (unsigned short*)ws; ws += MS * D * 2;           // 32 MiB
  unsigned short* Sreg = (unsigned short*)ws;
  const size_t s4_bytes = (size_t)Bn * S * S * 2;   // 128 MiB
  const size_t s1_bytes = (size_t)S * S * 2;        // 32 MiB
  size_t head = (size_t)(ws - (char*)d_ws);
  bool batched = ws_size >= head + s4_bytes + 8u * 1024 * 1024;
  ws += batched ? s4_bytes : s1_bytes;
  unsigned short* wqkb = (unsigned short*)ws; ws += (size_t)2048 * D * 2;
  unsigned short* wvb  = (unsigned short*)ws; ws += (size_t)D * D * 2;
  float* rsum = (float*)ws;                                             // 64 KiB
  unsigned short* xb = Sreg;  // alias: xb dead before any scores write

  // zero rowsum accumulator (graph-capture-safe stream op)
  hipMemsetAsync(rsum, 0, MS * sizeof(float), stream);

  // convert inputs to bf16
  cvt_f32_bf16<<<8192, 256, 0, stream>>>(x, xb, (long)MS * D);
  cvt_f32_bf16<<<512, 256, 0, stream>>>(Wq, wqkb, (long)D * D);
  cvt_f32_bf16<<<512, 256, 0, stream>>>(Wk, wqkb + (size_t)D * D, (long)D * D);
  cvt_f32_bf16<<<512, 256, 0, stream>>>(Wv, wvb, (long)D * D);

  // QK = x @ [Wq;Wk]^T  (M=16384, N=2048, K=1024)
  gemm_bt256<1><<<dim3(512, 1), 512, 0, stream>>>(
      xb, D, 0, wqkb, D, 0, QKb, 2048, 0, nullptr, 0, 8, D, 1.0f);
  // VT = Wv @ x^T  (M=1024, N=16384, K=1024) -> VTb [1024,16384]
  gemm_bt256<1><<<dim3(256, 1), 512, 0, stream>>>(
      wvb, D, 0, xb, D, 0, VTb, (int)MS, 0, nullptr, 0, 64, D, 1.0f);

  if (batched) {
    // P[b] = exp(Q_b K_b^T * scale), rowsums -> rsum  (M=N=4096, K=1024)
    gemm_bt256<2><<<dim3(256, Bn), 512, 0, stream>>>(
        QKb, 2048, (size_t)S * 2048,
        QKb + 1024, 2048, (size_t)S * 2048,
        Sreg, S, (size_t)S * S, rsum, S, 16, D, scale);
    // out[b] = (P_b @ V_b) / rsum  (M=4096, N=1024, K=4096)
    gemm_bt256<3><<<dim3(64, Bn), 512, 0, stream>>>(
        Sreg, S, (size_t)S * S,
        VTb, (int)MS, (size_t)S,
        out, D, (size_t)S * D, rsum, S, 4, S, 1.0f);
  } else {
    for (int b = 0; b < Bn; b++) {
      const unsigned short* Qx = QKb + (size_t)b * S * 2048;
      const unsigned short* Kx = Qx + 1024;
      gemm_bt256<2><<<dim3(256, 1), 512, 0, stream>>>(
          Qx, 2048, 0, Kx, 2048, 0, Sreg, S, 0, rsum + (size_t)b * S, 0,
          16, D, scale);
      gemm_bt256<3><<<dim3(64, 1), 512, 0, stream>>>(
          Sreg, S, 0, VTb + (size_t)b * S, (int)MS, 0,
          out + (size_t)b * S * D, D, 0, rsum + (size_t)b * S, 0, 4, S, 1.0f);
    }
  }
}

// Round 12
// 418.993 us; speedup vs baseline: 1.1352x; 1.1352x over previous
//
#include <hip/hip_runtime.h>
#include <cstdint>
#include <cstddef>

typedef __attribute__((ext_vector_type(8))) short short8;
typedef __attribute__((ext_vector_type(4))) float f32x4;

// ---------- helpers ----------
__device__ __forceinline__ unsigned short f2bf(float x) {
  union { float f; unsigned u; } v; v.f = x;
  unsigned r = (v.u + 0x7FFFu + ((v.u >> 16) & 1u)) >> 16;
  return (unsigned short)r;
}

#define GLOAD16(g, l)                                                    \
  __builtin_amdgcn_global_load_lds(                                      \
      (const __attribute__((address_space(1))) unsigned int*)(g),        \
      (__attribute__((address_space(3))) unsigned int*)(l), 16, 0, 0)

// inline-asm ds_read_b128: order-pinned so counted lgkmcnt is sound.
#define DSR(dst, addrv, imm)                                             \
  asm volatile("ds_read_b128 %0, %1 offset:%c2"                          \
               : "=&v"(dst) : "v"(addrv), "i"(imm))

// ---------- f32 -> bf16 conversion (memory-bound) ----------
__global__ __launch_bounds__(256) void cvt_f32_bf16(
    const float* __restrict__ in, unsigned short* __restrict__ out, long n) {
  long i = ((long)blockIdx.x * 256 + threadIdx.x) * 8;
  if (i >= n) return;
  const float4* p = (const float4*)(in + i);
  float4 a = p[0], b = p[1];
  short8 r;
  r[0] = (short)f2bf(a.x); r[1] = (short)f2bf(a.y);
  r[2] = (short)f2bf(a.z); r[3] = (short)f2bf(a.w);
  r[4] = (short)f2bf(b.x); r[5] = (short)f2bf(b.y);
  r[6] = (short)f2bf(b.z); r[7] = (short)f2bf(b.w);
  *(short8*)(out + i) = r;
}

// fused 3-weight conversion (one launch instead of three)
__global__ __launch_bounds__(256) void cvt_w3(
    const float* __restrict__ wa, const float* __restrict__ wb,
    const float* __restrict__ wc, unsigned short* __restrict__ oa,
    unsigned short* __restrict__ ob, unsigned short* __restrict__ oc) {
  int which = blockIdx.x >> 9;             // 512 blocks per weight (D*D/2048)
  long i = ((long)(blockIdx.x & 511) * 256 + threadIdx.x) * 8;
  const float* in = which == 0 ? wa : which == 1 ? wb : wc;
  unsigned short* out = which == 0 ? oa : which == 1 ? ob : oc;
  const float4* p = (const float4*)(in + i);
  float4 a = p[0], b = p[1];
  short8 r;
  r[0] = (short)f2bf(a.x); r[1] = (short)f2bf(a.y);
  r[2] = (short)f2bf(a.z); r[3] = (short)f2bf(a.w);
  r[4] = (short)f2bf(b.x); r[5] = (short)f2bf(b.y);
  r[6] = (short)f2bf(b.z); r[7] = (short)f2bf(b.w);
  *(short8*)(out + i) = r;
}

// sum 64 partials per row, store INVERSE (PV epilogue multiplies)
__global__ __launch_bounds__(256) void reduce_rsum(
    const float* __restrict__ part, float* __restrict__ outr,
    size_t stride, int n) {
  int i = blockIdx.x * 256 + threadIdx.x;
  if (i >= n) return;
  float s = 0.f;
#pragma unroll
  for (int p = 0; p < 64; p++) s += part[(size_t)p * stride + i];
  outr[i] = 1.0f / s;
}

// ---------- gemm_bt256: C[b][m,n] = f( sum_k A[b][m,k]*B[b][n,k] ) -------
// MODE 1: bf16 out (val*scale)
// MODE 2: bf16 out, exp(val*scale); per-wave partial rowsums stored to
//         rs[(bn*4+wn)*rsp + row] (plain stores, no atomics -- r11 showed
//         cross-XCD atomicAdd ping-pong cost ~47us on the scores dispatch)
// MODE 3: f32 out, val * rs[row]  (rs holds INVERSE rowsums)
// 256x256 tile, 8 waves (2M x 4N), BK=64, double-buffered LDS (128 KiB).
// Staging skeleton (r5/r9-verified): prefetch next tile, counted vmcnt(8);
// vmcnt(0) only on last tile; two barriers per K-tile.
// Compute body (r9-verified): 4 quadrant phases; phase p issues quadrant
// p+1's 4 asm ds_read_b128 then waits lgkmcnt(4) (leaves them in flight),
// sched_barrier(0), setprio(1), 16 MFMA, setprio(0), sched_barrier(0).
// Ledger: pre-loop q0(4)+B(8)=12 -> p0:+4=16,wait4 ; p1/p2:+4=8,wait4 ;
// p3: wait0.  (global_load_lds counts vmcnt, not lgkm.)
// LDS swizzle: 16B slot ^= (row&7); inverse applied on global source.
// Requires M%256==0, N%256==0, K%64==0, gridDim.x%8==0.
template <int MODE>
__global__ __launch_bounds__(512, 2) void gemm_bt256(
    const unsigned short* __restrict__ A, int lda, size_t asb,
    const unsigned short* __restrict__ B, int ldb, size_t bsb,
    void* __restrict__ C, int ldc, size_t csb,
    float* __restrict__ rs, int rss, size_t rsp,
    int nbn, int K, float scale) {
  __shared__ unsigned short As[2][256 * 64];
  __shared__ unsigned short Bs[2][256 * 64];

  A += (size_t)blockIdx.y * asb;
  B += (size_t)blockIdx.y * bsb;
  char* Cb = (char*)C + (size_t)blockIdx.y * csb * (MODE == 3 ? 4 : 2);
  rs += (size_t)blockIdx.y * rss;

  // XCD-aware block swizzle (gridDim.x multiple of 8)
  unsigned bid = blockIdx.x;
  unsigned cpx = gridDim.x >> 3;
  unsigned swz = (bid & 7u) * cpx + (bid >> 3);
  int bm = (int)(swz / (unsigned)nbn);
  int bn = (int)(swz % (unsigned)nbn);
  int m0 = bm * 256, n0 = bn * 256;

  int t512 = threadIdx.x;
  int lane = t512 & 63, wid = t512 >> 6;
  int wm = wid >> 2, wn = wid & 3;           // 2 x 4 wave grid
  int l15 = lane & 15, l4 = lane >> 4;

  // staging: thread t handles 16B chunks at rows srow+{0,64,128,192};
  // LDS slot = t&7 (linear dest), global chunk = slot ^ (srow&7).
  int srow = t512 >> 3;
  int g = (t512 & 7) ^ ((t512 >> 3) & 7);
  const unsigned short* pa = A + (size_t)(m0 + srow) * lda + g * 8;
  const unsigned short* pb = B + (size_t)(n0 + srow) * ldb + g * 8;

  f32x4 acc[8][4] = {};

  const int NT = K >> 6;

#define STAGE(jj, buf)                                                    \
  do {                                                                    \
    int _k0 = (jj) << 6;                                                  \
    _Pragma("unroll") for (int i = 0; i < 4; i++)                         \
        GLOAD16(pa + (size_t)(i * 64) * lda + _k0,                        \
                (char*)As[buf] + i * 8192 + t512 * 16);                   \
    _Pragma("unroll") for (int i = 0; i < 4; i++)                         \
        GLOAD16(pb + (size_t)(i * 64) * ldb + _k0,                        \
                (char*)Bs[buf] + i * 8192 + t512 * 16);                   \
  } while (0)

  // per-ks slot columns and fragment base addresses (mi/ni-independent)
  unsigned c0 = ((unsigned)l4) ^ (unsigned)(l15 & 7);
  unsigned c1 = (4u | (unsigned)l4) ^ (unsigned)(l15 & 7);
  unsigned rowA = (unsigned)(wm * 128 + l15) * 128u;
  unsigned rowB = (unsigned)(wn * 64 + l15) * 128u;

  // prologue: stage tile 0 into buffer 0
  STAGE(0, 0);

  for (int j = 0; j < NT; ++j) {
    int cur = j & 1;
    // pin iteration j-1's body before the stage below
    __builtin_amdgcn_sched_barrier(0);
    // barrier A: all waves done with buf[cur^1] (tile j-1)
    __builtin_amdgcn_s_barrier();
    if (j + 1 < NT) {
      STAGE(j + 1, cur ^ 1);
      // wait ONLY for tile j's 8 loads; the 8 just issued stay in flight
      asm volatile("s_waitcnt vmcnt(8)" ::: "memory");
    } else {
      asm volatile("s_waitcnt vmcnt(0)" ::: "memory");
    }
    // barrier B: every wave's tile-j loads have landed
    __builtin_amdgcn_s_barrier();

    unsigned baseA = (unsigned)(uintptr_t)(
        (__attribute__((address_space(3))) char*)(&As[cur][0]));
    unsigned baseB = (unsigned)(uintptr_t)(
        (__attribute__((address_space(3))) char*)(&Bs[cur][0]));
    unsigned aA0 = baseA + rowA + c0 * 16, aA1 = baseA + rowA + c1 * 16;
    unsigned aB0 = baseB + rowB + c0 * 16, aB1 = baseB + rowB + c1 * 16;

    short8 afq[2][2][2];  // [quadrant parity][m2][ks]
    short8 bfv[4][2];

    // issue quadrant 0 (4 reads) then all B (8 reads): outstanding = 12
    DSR(afq[0][0][0], aA0, 0);
    DSR(afq[0][0][1], aA1, 0);
    DSR(afq[0][1][0], aA0, 2048);
    DSR(afq[0][1][1], aA1, 2048);
#pragma unroll
    for (int ni = 0; ni < 4; ni++) {
      DSR(bfv[ni][0], aB0, ni * 2048);
      DSR(bfv[ni][1], aB1, ni * 2048);
    }

#pragma unroll
    for (int p = 0; p < 4; ++p) {
      if (p < 3) {
        const int mi0 = (p + 1) * 2;
        DSR(afq[(p + 1) & 1][0][0], aA0, mi0 * 2048);
        DSR(afq[(p + 1) & 1][0][1], aA1, mi0 * 2048);
        DSR(afq[(p + 1) & 1][1][0], aA0, (mi0 + 1) * 2048);
        DSR(afq[(p + 1) & 1][1][1], aA1, (mi0 + 1) * 2048);
        // drain everything except the 4 just issued
        asm volatile("s_waitcnt lgkmcnt(4)" ::: "memory");
      } else {
        asm volatile("s_waitcnt lgkmcnt(0)" ::: "memory");
      }
      __builtin_amdgcn_sched_barrier(0);  // rule #18 fence
      __builtin_amdgcn_s_setprio(1);
#pragma unroll
      for (int ks = 0; ks < 2; ks++)
#pragma unroll
        for (int m2 = 0; m2 < 2; m2++) {
          int mi = p * 2 + m2;
#pragma unroll
          for (int ni = 0; ni < 4; ni++)
            acc[mi][ni] = __builtin_amdgcn_mfma_f32_16x16x32_bf16(
                afq[p & 1][m2][ks], bfv[ni][ks], acc[mi][ni], 0, 0, 0);
        }
      __builtin_amdgcn_s_setprio(0);
      __builtin_amdgcn_sched_barrier(0);  // keep MFMA cluster in place
    }
  }
#undef STAGE

  // epilogue; row = m0 + wm*128 + mi*16 + l4*4 + jj, col = n0 + wn*64 + ni*16 + l15
  if constexpr (MODE == 2) {
    float sums[8][4];
#pragma unroll
    for (int mi = 0; mi < 8; mi++)
#pragma unroll
      for (int jj = 0; jj < 4; jj++) sums[mi][jj] = 0.f;
#pragma unroll
    for (int mi = 0; mi < 8; mi++)
#pragma unroll
      for (int ni = 0; ni < 4; ni++)
#pragma unroll
        for (int jj = 0; jj < 4; jj++) {
          int row = m0 + wm * 128 + mi * 16 + l4 * 4 + jj;
          int col = n0 + wn * 64 + ni * 16 + l15;
          float e = __expf(acc[mi][ni][jj] * scale);
          sums[mi][jj] += e;
          ((unsigned short*)Cb)[(size_t)row * ldc + col] = f2bf(e);
        }
    // per-wave partial: reduce 16 col-lanes, ONE plain store per row group
    size_t pslot = (size_t)(bn * 4 + wn) * rsp;
#pragma unroll
    for (int mi = 0; mi < 8; mi++)
#pragma unroll
      for (int jj = 0; jj < 4; jj++) {
        float s = sums[mi][jj];
        s += __shfl_xor(s, 1);
        s += __shfl_xor(s, 2);
        s += __shfl_xor(s, 4);
        s += __shfl_xor(s, 8);
        if (l15 == 0) {
          int row = m0 + wm * 128 + mi * 16 + l4 * 4 + jj;
          rs[pslot + row] = s;
        }
      }
  } else {
#pragma unroll
    for (int mi = 0; mi < 8; mi++) {
      float inv[4];
      if constexpr (MODE == 3) {
#pragma unroll
        for (int jj = 0; jj < 4; jj++) {
          int row = m0 + wm * 128 + mi * 16 + l4 * 4 + jj;
          inv[jj] = rs[row];  // already inverted by reduce_rsum
        }
      }
#pragma unroll
      for (int ni = 0; ni < 4; ni++)
#pragma unroll
        for (int jj = 0; jj < 4; jj++) {
          int row = m0 + wm * 128 + mi * 16 + l4 * 4 + jj;
          int col = n0 + wn * 64 + ni * 16 + l15;
          float val = acc[mi][ni][jj];
          if constexpr (MODE == 1)
            ((unsigned short*)Cb)[(size_t)row * ldc + col] = f2bf(val * scale);
          else
            ((float*)Cb)[(size_t)row * ldc + col] = val * inv[jj];
        }
    }
  }
}

// ---------- launcher ----------
extern "C" void kernel_launch(void* const* d_in, const int* in_sizes, int n_in,
                              void* d_out, int out_size, void* d_ws, size_t ws_size,
                              hipStream_t stream) {
  (void)in_sizes; (void)n_in; (void)out_size;
  const float* x  = (const float*)d_in[0];
  const float* Wq = (const float*)d_in[1];
  const float* Wk = (const float*)d_in[2];
  const float* Wv = (const float*)d_in[3];
  float* out = (float*)d_out;

  const int Bn = 4, S = 4096, D = 1024;
  const size_t MS = (size_t)Bn * S;  // 16384
  const float scale = 0.03125f;      // 1/sqrt(1024)

  // ---- workspace layout ----
  char* ws = (char*)d_ws;
  unsigned short* QKb = (unsigned short*)ws; ws += MS * 2048 * 2;        // 64 MiB
  unsigned short* VTb = (unsigned short*)ws; ws += MS * D * 2;           // 32 MiB
  unsigned short* Sreg = (unsigned short*)ws;
  const size_t s4_bytes = (size_t)Bn * S * S * 2;   // 128 MiB
  const size_t s1_bytes = (size_t)S * S * 2;        // 32 MiB
  size_t head = (size_t)(ws - (char*)d_ws);
  bool batched = ws_size >= head + s4_bytes + 16u * 1024 * 1024;
  ws += batched ? s4_bytes : s1_bytes;
  unsigned short* wqkb = (unsigned short*)ws; ws += (size_t)2048 * D * 2;
  unsigned short* wvb  = (unsigned short*)ws; ws += (size_t)D * D * 2;
  float* rpart = (float*)ws; ws += 64 * MS * sizeof(float);              // 4 MiB
  float* rinv  = (float*)ws;                                             // 64 KiB
  unsigned short* xb = Sreg;  // alias: xb dead before any scores write

  // convert inputs to bf16
  cvt_f32_bf16<<<8192, 256, 0, stream>>>(x, xb, (long)MS * D);
  cvt_w3<<<1536, 256, 0, stream>>>(Wq, Wk, Wv, wqkb, wqkb + (size_t)D * D, wvb);

  // QK = x @ [Wq;Wk]^T  (M=16384, N=2048, K=1024)
  gemm_bt256<1><<<dim3(512, 1), 512, 0, stream>>>(
      xb, D, 0, wqkb, D, 0, QKb, 2048, 0, nullptr, 0, 0, 8, D, 1.0f);
  // VT = Wv @ x^T  (M=1024, N=16384, K=1024) -> VTb [1024,16384]
  gemm_bt256<1><<<dim3(256, 1), 512, 0, stream>>>(
      wvb, D, 0, xb, D, 0, VTb, (int)MS, 0, nullptr, 0, 0, 64, D, 1.0f);

  if (batched) {
    // P[b] = exp(Q_b K_b^T * scale); partial rowsums -> rpart
    gemm_bt256<2><<<dim3(256, Bn), 512, 0, stream>>>(
        QKb, 2048, (size_t)S * 2048,
        QKb + 1024, 2048, (size_t)S * 2048,
        Sreg, S, (size_t)S * S, rpart, S, MS, 16, D, scale);
    // inverse rowsums
    reduce_rsum<<<(int)(MS / 256), 256, 0, stream>>>(rpart, rinv, MS, (int)MS);
    // out[b] = (P_b @ V_b) * rinv  (M=4096, N=1024, K=4096)
    gemm_bt256<3><<<dim3(64, Bn), 512, 0, stream>>>(
        Sreg, S, (size_t)S * S,
        VTb, (int)MS, (size_t)S,
        out, D, (size_t)S * D, rinv, S, 0, 4, S, 1.0f);
  } else {
    for (int b = 0; b < Bn; b++) {
      const unsigned short* Qx = QKb + (size_t)b * S * 2048;
      const unsigned short* Kx = Qx + 1024;
      gemm_bt256<2><<<dim3(256, 1), 512, 0, stream>>>(
          Qx, 2048, 0, Kx, 2048, 0, Sreg, S, 0,
          rpart + (size_t)b * S, 0, MS, 16, D, scale);
      reduce_rsum<<<S / 256, 256, 0, stream>>>(
          rpart + (size_t)b * S, rinv + (size_t)b * S, MS, S);
      gemm_bt256<3><<<dim3(64, 1), 512, 0, stream>>>(
          Sreg, S, 0, VTb + (size_t)b * S, (int)MS, 0,
          out + (size_t)b * S * D, D, 0, rinv + (size_t)b * S, 0, 0,
          4, S, 1.0f);
    }
  }
}